// Round 6
// baseline (244.421 us; speedup 1.0000x reference)
//
#include <hip/hip_runtime.h>
#include <hip/hip_bf16.h>
#include <stdint.h>

typedef __hip_bfloat16 bf16;
typedef __attribute__((ext_vector_type(8))) short bh8;
typedef __attribute__((ext_vector_type(4))) float f32x4;

#define MFMA16(a, b, c) __builtin_amdgcn_mfma_f32_16x16x32_bf16((a), (b), (c), 0, 0, 0)

typedef const __attribute__((address_space(1))) void* gas1_t;
typedef __attribute__((address_space(3))) void* las3_t;

__device__ __forceinline__ void gload_lds16(const void* g, void* l) {
  __builtin_amdgcn_global_load_lds((gas1_t)g, (las3_t)l, 16, 0, 0);
}

__device__ __forceinline__ float bfu2f(unsigned short u) {
  union { unsigned int i; float f; } c;
  c.i = (unsigned int)u << 16;
  return c.f;
}

// ---------------- cast fp32 -> bf16 (vectorized) ----------------
__global__ __launch_bounds__(256) void cast_f32_bf16(const float* __restrict__ x,
                                                     bf16* __restrict__ y, int n4) {
  int i = blockIdx.x * 256 + threadIdx.x;
  if (i >= n4) return;
  float4 v = ((const float4*)x)[i];
  union { ushort4 u; bf16 b[4]; } o;
  o.b[0] = __float2bfloat16(v.x);
  o.b[1] = __float2bfloat16(v.y);
  o.b[2] = __float2bfloat16(v.z);
  o.b[3] = __float2bfloat16(v.w);
  ((ushort4*)y)[i] = o.u;
}

// ---------------- transpose + cast: W (R x C) fp32 -> WT (C x R) bf16 ----------------
__global__ __launch_bounds__(256) void transpose_cast(const float* __restrict__ W,
                                                      bf16* __restrict__ WT, int R, int C) {
  __shared__ float tile[32][33];
  const int tx = threadIdx.x & 31, ty = threadIdx.x >> 5;
  const int bx = blockIdx.x, by = blockIdx.y;
#pragma unroll
  for (int p = 0; p < 4; ++p)
    tile[ty + p * 8][tx] = W[(long)(by * 32 + ty + p * 8) * C + bx * 32 + tx];
  __syncthreads();
#pragma unroll
  for (int p = 0; p < 4; ++p)
    WT[(long)(bx * 32 + ty + p * 8) * R + by * 32 + tx] = __float2bfloat16(tile[tx][ty + p * 8]);
}

// ---------------- GEMM split-K: C(MxN) = A(MxK) * BT(NxK)^T ----------------
// BK=64, XOR-swizzled LDS (T2), 128x128 tile, 4 waves (2x2), grid.z = K-chunk.
template <bool BF16OUT>
__global__ __launch_bounds__(256) void gemm_bt_sk(const bf16* __restrict__ A,
                                                  const bf16* __restrict__ BT,
                                                  void* __restrict__ C0, void* __restrict__ C1,
                                                  int M, int N, int Kd, int nKs) {
  __shared__ bf16 As[128 * 64];
  __shared__ bf16 Bs[128 * 64];
  const int tid = threadIdx.x, lane = tid & 63, wid = tid >> 6;
  const int wr = wid >> 1, wc = wid & 1;
  const int bx = blockIdx.x, by = blockIdx.y, z = blockIdx.z;

  f32x4 acc[4][4];
#pragma unroll
  for (int m = 0; m < 4; ++m)
#pragma unroll
    for (int n = 0; n < 4; ++n)
#pragma unroll
      for (int r = 0; r < 4; ++r) acc[m][n][r] = 0.0f;

  const long Abase = (long)(by * 128) * Kd;
  const long Bbase = (long)(bx * 128) * Kd;
  const int lr = lane & 15, lh = lane >> 4;
  const int k00 = z * nKs * 64;

  for (int kt = 0; kt < nKs; ++kt) {
    __syncthreads();
    const int k0 = k00 + kt * 64;
#pragma unroll
    for (int i = 0; i < 4; ++i) {
      const int cb = i * 256 + wid * 64;
      const int c = cb + lane;
      const int row = c >> 3, s = c & 7;
      gload_lds16(A + Abase + (long)row * Kd + k0 + (s ^ (row & 7)) * 8, (char*)As + cb * 16);
      gload_lds16(BT + Bbase + (long)row * Kd + k0 + (s ^ (row & 7)) * 8, (char*)Bs + cb * 16);
    }
    __syncthreads();

#pragma unroll
    for (int kk = 0; kk < 2; ++kk) {
      bh8 af[4], bfv[4];
#pragma unroll
      for (int m = 0; m < 4; ++m)
        af[m] = *(const bh8*)((const char*)As +
                              (((wr * 64 + m * 16 + lr) * 128 + kk * 64 + lh * 16) ^
                               ((lr & 7) << 4)));
#pragma unroll
      for (int n = 0; n < 4; ++n)
        bfv[n] = *(const bh8*)((const char*)Bs +
                               (((wc * 64 + n * 16 + lr) * 128 + kk * 64 + lh * 16) ^
                                ((lr & 7) << 4)));
#pragma unroll
      for (int m = 0; m < 4; ++m)
#pragma unroll
        for (int n = 0; n < 4; ++n) acc[m][n] = MFMA16(af[m], bfv[n], acc[m][n]);
    }
  }

  const int r0 = by * 128 + wr * 64, c0 = bx * 128 + wc * 64;
  const int lrow = lh * 4;
  if (BF16OUT) {
    bf16* P = (bf16*)(z == 0 ? C0 : C1);
#pragma unroll
    for (int m = 0; m < 4; ++m)
#pragma unroll
      for (int n = 0; n < 4; ++n)
#pragma unroll
        for (int r = 0; r < 4; ++r)
          P[(long)(r0 + m * 16 + lrow + r) * N + c0 + n * 16 + lr] =
              __float2bfloat16(acc[m][n][r]);
  } else {
    float* P = (float*)(z == 0 ? C0 : C1);
#pragma unroll
    for (int m = 0; m < 4; ++m)
#pragma unroll
      for (int n = 0; n < 4; ++n)
#pragma unroll
        for (int r = 0; r < 4; ++r)
          P[(long)(r0 + m * 16 + lrow + r) * N + c0 + n * 16 + lr] = acc[m][n][r];
  }
}

// ---------------- out += partial1 (fp32, vectorized) ----------------
__global__ __launch_bounds__(256) void out_reduce(float* __restrict__ out,
                                                  const float* __restrict__ p1, int n4) {
  int i = blockIdx.x * 256 + threadIdx.x;
  if (i >= n4) return;
  float4 a = ((const float4*)out)[i];
  float4 b = ((const float4*)p1)[i];
  a.x += b.x; a.y += b.y; a.z += b.z; a.w += b.w;
  ((float4*)out)[i] = a;
}

// ---------------- RoPE (NeoX) + sum 2 bf16 qkv partials + split ----------------
// Q is PRE-SCALED by 1/sqrt(D) here so attn skips the per-element scale.
__global__ __launch_bounds__(256) void rope_split(const bf16* __restrict__ P0,
                                                  const bf16* __restrict__ P1,
                                                  const int* __restrict__ pos_ids,
                                                  bf16* __restrict__ Qb, bf16* __restrict__ Kb,
                                                  bf16* __restrict__ VbT) {
  const int t = blockIdx.x;
  const int tid = threadIdx.x;
  const float pos = (float)pos_ids[t];
  const float qscale = 0.08838834764831845f;  // 1/sqrt(128)
  const ushort* r0 = (const ushort*)(P0 + (long)t * 3072);
  const ushort* r1 = (const ushort*)(P1 + (long)t * 3072);
  for (int i = tid; i < 512; i += 256) {
    const int kvh = i >> 7, d = i & 127;
    const float v = bfu2f(r0[2560 + i]) + bfu2f(r1[2560 + i]);
    VbT[(long)(kvh * 128 + d) * 2048 + t] = __float2bfloat16(v);
  }
  for (int i = tid; i < 1280; i += 256) {
    const int hh = i >> 6, d = i & 63;
    const float inv = exp2f((float)d * -0.2076205059304594f);  // 10000^(-d/64)
    const float ang = pos * inv;
    const float c = cosf(ang), s = sinf(ang);
    const float x1 = bfu2f(r0[hh * 128 + d]) + bfu2f(r1[hh * 128 + d]);
    const float x2 = bfu2f(r0[hh * 128 + d + 64]) + bfu2f(r1[hh * 128 + d + 64]);
    const float o1 = x1 * c - x2 * s, o2 = x2 * c + x1 * s;
    if (hh < 16) {
      Qb[(long)t * 2048 + hh * 128 + d] = __float2bfloat16(o1 * qscale);
      Qb[(long)t * 2048 + hh * 128 + d + 64] = __float2bfloat16(o2 * qscale);
    } else {
      Kb[t * 512 + (hh - 16) * 128 + d] = __float2bfloat16(o1);
      Kb[t * 512 + (hh - 16) * 128 + d + 64] = __float2bfloat16(o2);
    }
  }
}

// ---------------- Flash attention partials: swapped-QK in-register softmax ----------------
// S^T = mfma(K_frag, Q_frag): lane holds 16 P values of q-row (lane&15).
// K rows fed in sigma-order (key = kc*32 + (lr>>2)*8 + b*4 + (lr&3)) so the S output
// registers ARE the PV A-fragment (key == k-position). P never touches LDS.
__global__ __launch_bounds__(256, 4) void attn_partial(const bf16* __restrict__ Qb,
                                                       const bf16* __restrict__ Kb,
                                                       const bf16* __restrict__ VbT,
                                                       bf16* __restrict__ Pctx,
                                                       float* __restrict__ ML) {
  const int h = blockIdx.x;
  const int qb = 31 - blockIdx.y;  // heavy blocks dispatch first
  const int z = blockIdx.z;
  const int kh = h >> 2;
  const int tid = threadIdx.x, lane = tid & 63, w = tid >> 6;
  const int pid = (h * 32 + qb) * 2 + z;

  const int nt = qb + 1;
  const int half = (nt + 1) >> 1;
  const int kt0 = z * half;
  const int kt1 = (z == 0) ? half : nt;

  if (kt0 >= kt1) {  // empty chunk: neutral ML + zeroed partial
    if (tid < 64) {
      ML[pid * 128 + tid] = -1e30f;
      ML[pid * 128 + 64 + tid] = 0.0f;
    }
    ushort4 z4 = make_ushort4(0, 0, 0, 0);
    ushort4* pz = (ushort4*)(Pctx + (long)pid * 8192);
    for (int j = tid; j < 2048; j += 256) pz[j] = z4;
    return;
  }

  __shared__ bf16 Kl[64 * 128];  // swizzle bits: (row&3)|((row&8)>>1)
  __shared__ bf16 Vt[128 * 64];  // swizzle bits: row&7

  const int lr = lane & 15, lh = lane >> 4;
  const int q0w = qb * 64 + w * 16;

  bh8 qf[4];
#pragma unroll
  for (int dc = 0; dc < 4; ++dc)
    qf[dc] = *(const bh8*)&Qb[(long)(q0w + lr) * 2048 + h * 128 + dc * 32 + lh * 8];

  f32x4 ctx[8];
#pragma unroll
  for (int i = 0; i < 8; ++i)
#pragma unroll
    for (int r = 0; r < 4; ++r) ctx[i][r] = 0.0f;
  float mrun = -1e30f, lrun = 0.0f;

  for (int kt = kt0; kt < kt1; ++kt) {
    __syncthreads();
    // stage K tile 64x128: linear LDS dest, source chunk-swizzled by (row&3)|((row&8)>>1)
    const long Kbase = ((long)(kt * 64) * 4 + kh) * 128;
#pragma unroll
    for (int i = 0; i < 4; ++i) {
      const int cb = i * 256 + w * 64;
      const int c = cb + lane;
      const int krow = c >> 4, s = c & 15;
      const int g = s ^ ((krow & 3) | ((krow & 8) >> 1));
      gload_lds16(Kb + Kbase + (long)krow * 512 + g * 8, (char*)Kl + cb * 16);
    }
    // stage V^T tile 128x64: source chunk-swizzled by row&7
    const long Vbase = (long)kh * 128 * 2048 + kt * 64;
#pragma unroll
    for (int i = 0; i < 4; ++i) {
      const int cb = i * 256 + w * 64;
      const int c = cb + lane;
      const int vrow = c >> 3, s = c & 7;
      gload_lds16(VbT + Vbase + (long)vrow * 2048 + (s ^ (vrow & 7)) * 8, (char*)Vt + cb * 16);
    }
    __syncthreads();

    // S^T = K . Q^T in sigma key-order; lane (lr,lh) reg (kc,b,r) holds
    // S[key = kc*32 + lh*8 + b*4 + r][q = lr]   (Q pre-scaled by 1/sqrt(D))
    f32x4 S[2][2];
#pragma unroll
    for (int kc = 0; kc < 2; ++kc)
#pragma unroll
      for (int b = 0; b < 2; ++b) {
#pragma unroll
        for (int r = 0; r < 4; ++r) S[kc][b][r] = 0.0f;
        const int key = kc * 32 + ((lr >> 2) << 3) + b * 4 + (lr & 3);
        const int kbase = key * 256 + lh * 16;
#pragma unroll
        for (int dc = 0; dc < 4; ++dc) {
          bh8 kf = *(const bh8*)((const char*)Kl + ((kbase + dc * 64) ^ ((lr & 7) << 4)));
          S[kc][b] = MFMA16(kf, qf[dc], S[kc][b]);
        }
      }

    // causal mask on the diagonal tile only
    if (kt == qb) {
      const int qg = q0w + lr;
#pragma unroll
      for (int kc = 0; kc < 2; ++kc)
#pragma unroll
        for (int b = 0; b < 2; ++b)
#pragma unroll
          for (int r = 0; r < 4; ++r) {
            const int kg = kt * 64 + kc * 32 + lh * 8 + b * 4 + r;
            if (kg > qg) S[kc][b][r] = -1e30f;
          }
    }

    // row max: 15 in-lane fmax + 2 shfl (row = q = lr)
    float pm = -1e30f;
#pragma unroll
    for (int kc = 0; kc < 2; ++kc)
#pragma unroll
      for (int b = 0; b < 2; ++b)
#pragma unroll
        for (int r = 0; r < 4; ++r) pm = fmaxf(pm, S[kc][b][r]);
    pm = fmaxf(pm, __shfl_xor(pm, 16, 64));
    pm = fmaxf(pm, __shfl_xor(pm, 32, 64));

    // defer-max: rescale only when some row grew past mrun + 4
    if (__any(pm > mrun + 4.0f)) {
      const float mnew = fmaxf(mrun, pm);
      const float alpha = __expf(mrun - mnew);
      mrun = mnew;
      lrun *= alpha;
      float a4[4];
#pragma unroll
      for (int r = 0; r < 4; ++r) a4[r] = __shfl(alpha, lh * 4 + r, 64);
#pragma unroll
      for (int i = 0; i < 8; ++i)
#pragma unroll
        for (int r = 0; r < 4; ++r) ctx[i][r] *= a4[r];
    }

    // P = exp(S - mrun), packed in-register as the PV A-fragment
    bh8 pa[2];
#pragma unroll
    for (int kc = 0; kc < 2; ++kc) {
      union { bh8 v; bf16 e[8]; } pk;
#pragma unroll
      for (int b = 0; b < 2; ++b)
#pragma unroll
        for (int r = 0; r < 4; ++r) {
          const float p = __expf(S[kc][b][r] - mrun);
          lrun += p;
          pk.e[b * 4 + r] = __float2bfloat16(p);
        }
      pa[kc] = pk.v;
    }

    // PV: ctx += P(16x64) * V(64x128)
#pragma unroll
    for (int kc = 0; kc < 2; ++kc)
#pragma unroll
      for (int dblk = 0; dblk < 8; ++dblk) {
        const int vrow = dblk * 16 + lr;
        const int voff = (vrow * 128 + kc * 64 + lh * 16) ^ ((lr & 7) << 4);
        bh8 vb = *(const bh8*)((const char*)Vt + voff);
        ctx[dblk] = MFMA16(pa[kc], vb, ctx[dblk]);
      }
  }

  // epilogue: reduce row sums (2 shfl), write unnormalized partial + (m,l)
  float l = lrun;
  l += __shfl_xor(l, 16, 64);
  l += __shfl_xor(l, 32, 64);
  if (lh == 0) {
    ML[pid * 128 + w * 16 + lr] = mrun;
    ML[pid * 128 + 64 + w * 16 + lr] = l;
  }
#pragma unroll
  for (int dblk = 0; dblk < 8; ++dblk)
#pragma unroll
    for (int r = 0; r < 4; ++r)
      Pctx[(long)pid * 8192 + (w * 16 + lh * 4 + r) * 128 + dblk * 16 + lr] =
          __float2bfloat16(ctx[dblk][r]);
}

// ---------------- merge 2 partials -> normalized ctx (bf16, [t][h*128+d]) ----------------
__global__ __launch_bounds__(256) void attn_merge(const bf16* __restrict__ Pctx,
                                                  const float* __restrict__ ML,
                                                  bf16* __restrict__ out) {
  const int h = blockIdx.x, qb = blockIdx.y;
  const int tid = threadIdx.x;
  const int r = tid >> 2, seg = tid & 3;
  const int pid0 = (h * 32 + qb) * 2;
  const float m0 = ML[pid0 * 128 + r], l0 = ML[pid0 * 128 + 64 + r];
  const float m1 = ML[pid0 * 128 + 128 + r], l1 = ML[pid0 * 128 + 192 + r];
  const float m = fmaxf(m0, m1);
  float a0 = __expf(m0 - m), a1 = __expf(m1 - m);
  const float inv = 1.0f / (l0 * a0 + l1 * a1);
  a0 *= inv;
  a1 *= inv;
  const ushort* p0 = (const ushort*)(Pctx + (long)pid0 * 8192 + r * 128 + seg * 32);
  const ushort* p1 = p0 + 8192;
  bf16* o = out + (long)(qb * 64 + r) * 2048 + h * 128 + seg * 32;
#pragma unroll
  for (int j = 0; j < 4; ++j) {
    union { bh8 v; ushort s[8]; } v0, v1;
    v0.v = *(const bh8*)(p0 + j * 8);
    v1.v = *(const bh8*)(p1 + j * 8);
    union { ushort4 u; bf16 b[4]; } o0, o1;
#pragma unroll
    for (int e = 0; e < 4; ++e) {
      o0.b[e] = __float2bfloat16(bfu2f(v0.s[e]) * a0 + bfu2f(v1.s[e]) * a1);
      o1.b[e] = __float2bfloat16(bfu2f(v0.s[e + 4]) * a0 + bfu2f(v1.s[e + 4]) * a1);
    }
    *(ushort4*)(o + j * 8) = o0.u;
    *(ushort4*)(o + j * 8 + 4) = o1.u;
  }
}

// ---------------- launch ----------------
extern "C" void kernel_launch(void* const* d_in, const int* in_sizes, int n_in,
                              void* d_out, int out_size, void* d_ws, size_t ws_size,
                              hipStream_t stream) {
  const float* hs = (const float*)d_in[0];
  const int* pos = (const int*)d_in[1];
  const float* Wqkv = (const float*)d_in[2];
  const float* Wo = (const float*)d_in[3];
  char* ws = (char*)d_ws;

  bf16* hsb = (bf16*)(ws);
  bf16* ctx = (bf16*)(ws);
  bf16* wqkvT = (bf16*)(ws + (8l << 20));
  bf16* Qb = (bf16*)(ws + (8l << 20));
  bf16* Kb = (bf16*)(ws + (16l << 20));
  bf16* VbT = (bf16*)(ws + (18l << 20));
  bf16* woT = (bf16*)(ws + (20l << 20));
  bf16* qkvP0 = (bf16*)(ws + (28l << 20));
  bf16* qkvP1 = (bf16*)(ws + (40l << 20));
  bf16* Pctx = (bf16*)(ws + (28l << 20));
  float* ML = (float*)(ws + (44l << 20));
  float* outP1 = (float*)(ws + (28l << 20));

  cast_f32_bf16<<<4096, 256, 0, stream>>>(hs, hsb, 2048 * 2048 / 4);
  transpose_cast<<<dim3(3072 / 32, 2048 / 32), 256, 0, stream>>>(Wqkv, wqkvT, 2048, 3072);
  transpose_cast<<<dim3(2048 / 32, 2048 / 32), 256, 0, stream>>>(Wo, woT, 2048, 2048);
  gemm_bt_sk<true><<<dim3(24, 16, 2), 256, 0, stream>>>(hsb, wqkvT, qkvP0, qkvP1,
                                                        2048, 3072, 2048, 16);
  rope_split<<<2048, 256, 0, stream>>>(qkvP0, qkvP1, pos, Qb, Kb, VbT);
  attn_partial<<<dim3(16, 32, 2), 256, 0, stream>>>(Qb, Kb, VbT, Pctx, ML);
  attn_merge<<<dim3(16, 32), 256, 0, stream>>>(Pctx, ML, ctx);
  gemm_bt_sk<false><<<dim3(16, 16, 2), 256, 0, stream>>>(ctx, woT, d_out, outP1,
                                                         2048, 2048, 2048, 16);
  out_reduce<<<4096, 256, 0, stream>>>((float*)d_out, outP1, 2048 * 2048 / 4);
}

// Round 7
// 229.896 us; speedup vs baseline: 1.0632x; 1.0632x over previous
//
#include <hip/hip_runtime.h>
#include <hip/hip_bf16.h>
#include <stdint.h>

typedef __hip_bfloat16 bf16;
typedef __attribute__((ext_vector_type(8))) short bh8;
typedef __attribute__((ext_vector_type(4))) float f32x4;

#define MFMA16(a, b, c) __builtin_amdgcn_mfma_f32_16x16x32_bf16((a), (b), (c), 0, 0, 0)

typedef const __attribute__((address_space(1))) void* gas1_t;
typedef __attribute__((address_space(3))) void* las3_t;

__device__ __forceinline__ void gload_lds16(const void* g, void* l) {
  __builtin_amdgcn_global_load_lds((gas1_t)g, (las3_t)l, 16, 0, 0);
}

__device__ __forceinline__ float bfu2f(unsigned short u) {
  union { unsigned int i; float f; } c;
  c.i = (unsigned int)u << 16;
  return c.f;
}

// ---------------- cast fp32 -> bf16 (vectorized) ----------------
__global__ __launch_bounds__(256) void cast_f32_bf16(const float* __restrict__ x,
                                                     bf16* __restrict__ y, int n4) {
  int i = blockIdx.x * 256 + threadIdx.x;
  if (i >= n4) return;
  float4 v = ((const float4*)x)[i];
  union { ushort4 u; bf16 b[4]; } o;
  o.b[0] = __float2bfloat16(v.x);
  o.b[1] = __float2bfloat16(v.y);
  o.b[2] = __float2bfloat16(v.z);
  o.b[3] = __float2bfloat16(v.w);
  ((ushort4*)y)[i] = o.u;
}

// ---------------- transpose + cast: W (R x C) fp32 -> WT (C x R) bf16 ----------------
__global__ __launch_bounds__(256) void transpose_cast(const float* __restrict__ W,
                                                      bf16* __restrict__ WT, int R, int C) {
  __shared__ float tile[32][33];
  const int tx = threadIdx.x & 31, ty = threadIdx.x >> 5;
  const int bx = blockIdx.x, by = blockIdx.y;
#pragma unroll
  for (int p = 0; p < 4; ++p)
    tile[ty + p * 8][tx] = W[(long)(by * 32 + ty + p * 8) * C + bx * 32 + tx];
  __syncthreads();
#pragma unroll
  for (int p = 0; p < 4; ++p)
    WT[(long)(bx * 32 + ty + p * 8) * R + by * 32 + tx] = __float2bfloat16(tile[tx][ty + p * 8]);
}

// ---------------- GEMM split-K: C(MxN) = A(MxK) * BT(NxK)^T ----------------
// BK=64, XOR-swizzled LDS (T2), 128x128 tile, 4 waves (2x2), grid.z = K-chunk.
template <bool BF16OUT>
__global__ __launch_bounds__(256) void gemm_bt_sk(const bf16* __restrict__ A,
                                                  const bf16* __restrict__ BT,
                                                  void* __restrict__ C0, void* __restrict__ C1,
                                                  int M, int N, int Kd, int nKs) {
  __shared__ bf16 As[128 * 64];
  __shared__ bf16 Bs[128 * 64];
  const int tid = threadIdx.x, lane = tid & 63, wid = tid >> 6;
  const int wr = wid >> 1, wc = wid & 1;
  const int bx = blockIdx.x, by = blockIdx.y, z = blockIdx.z;

  f32x4 acc[4][4];
#pragma unroll
  for (int m = 0; m < 4; ++m)
#pragma unroll
    for (int n = 0; n < 4; ++n)
#pragma unroll
      for (int r = 0; r < 4; ++r) acc[m][n][r] = 0.0f;

  const long Abase = (long)(by * 128) * Kd;
  const long Bbase = (long)(bx * 128) * Kd;
  const int lr = lane & 15, lh = lane >> 4;
  const int k00 = z * nKs * 64;

  for (int kt = 0; kt < nKs; ++kt) {
    __syncthreads();
    const int k0 = k00 + kt * 64;
#pragma unroll
    for (int i = 0; i < 4; ++i) {
      const int cb = i * 256 + wid * 64;
      const int c = cb + lane;
      const int row = c >> 3, s = c & 7;
      gload_lds16(A + Abase + (long)row * Kd + k0 + (s ^ (row & 7)) * 8, (char*)As + cb * 16);
      gload_lds16(BT + Bbase + (long)row * Kd + k0 + (s ^ (row & 7)) * 8, (char*)Bs + cb * 16);
    }
    __syncthreads();

#pragma unroll
    for (int kk = 0; kk < 2; ++kk) {
      bh8 af[4], bfv[4];
#pragma unroll
      for (int m = 0; m < 4; ++m)
        af[m] = *(const bh8*)((const char*)As +
                              (((wr * 64 + m * 16 + lr) * 128 + kk * 64 + lh * 16) ^
                               ((lr & 7) << 4)));
#pragma unroll
      for (int n = 0; n < 4; ++n)
        bfv[n] = *(const bh8*)((const char*)Bs +
                               (((wc * 64 + n * 16 + lr) * 128 + kk * 64 + lh * 16) ^
                                ((lr & 7) << 4)));
#pragma unroll
      for (int m = 0; m < 4; ++m)
#pragma unroll
        for (int n = 0; n < 4; ++n) acc[m][n] = MFMA16(af[m], bfv[n], acc[m][n]);
    }
  }

  const int r0 = by * 128 + wr * 64, c0 = bx * 128 + wc * 64;
  const int lrow = lh * 4;
  if (BF16OUT) {
    bf16* P = (bf16*)(z == 0 ? C0 : C1);
#pragma unroll
    for (int m = 0; m < 4; ++m)
#pragma unroll
      for (int n = 0; n < 4; ++n)
#pragma unroll
        for (int r = 0; r < 4; ++r)
          P[(long)(r0 + m * 16 + lrow + r) * N + c0 + n * 16 + lr] =
              __float2bfloat16(acc[m][n][r]);
  } else {
    float* P = (float*)(z == 0 ? C0 : C1);
#pragma unroll
    for (int m = 0; m < 4; ++m)
#pragma unroll
      for (int n = 0; n < 4; ++n)
#pragma unroll
        for (int r = 0; r < 4; ++r)
          P[(long)(r0 + m * 16 + lrow + r) * N + c0 + n * 16 + lr] = acc[m][n][r];
  }
}

// ---------------- out += partial1 (fp32, vectorized) ----------------
__global__ __launch_bounds__(256) void out_reduce(float* __restrict__ out,
                                                  const float* __restrict__ p1, int n4) {
  int i = blockIdx.x * 256 + threadIdx.x;
  if (i >= n4) return;
  float4 a = ((const float4*)out)[i];
  float4 b = ((const float4*)p1)[i];
  a.x += b.x; a.y += b.y; a.z += b.z; a.w += b.w;
  ((float4*)out)[i] = a;
}

// ---------------- RoPE (NeoX) + sum 2 bf16 qkv partials + split ----------------
// Q is PRE-SCALED by 1/sqrt(D) here so attn skips the per-element scale.
__global__ __launch_bounds__(256) void rope_split(const bf16* __restrict__ P0,
                                                  const bf16* __restrict__ P1,
                                                  const int* __restrict__ pos_ids,
                                                  bf16* __restrict__ Qb, bf16* __restrict__ Kb,
                                                  bf16* __restrict__ VbT) {
  const int t = blockIdx.x;
  const int tid = threadIdx.x;
  const float pos = (float)pos_ids[t];
  const float qscale = 0.08838834764831845f;  // 1/sqrt(128)
  const ushort* r0 = (const ushort*)(P0 + (long)t * 3072);
  const ushort* r1 = (const ushort*)(P1 + (long)t * 3072);
  for (int i = tid; i < 512; i += 256) {
    const int kvh = i >> 7, d = i & 127;
    const float v = bfu2f(r0[2560 + i]) + bfu2f(r1[2560 + i]);
    VbT[(long)(kvh * 128 + d) * 2048 + t] = __float2bfloat16(v);
  }
  for (int i = tid; i < 1280; i += 256) {
    const int hh = i >> 6, d = i & 63;
    const float inv = exp2f((float)d * -0.2076205059304594f);  // 10000^(-d/64)
    const float ang = pos * inv;
    const float c = cosf(ang), s = sinf(ang);
    const float x1 = bfu2f(r0[hh * 128 + d]) + bfu2f(r1[hh * 128 + d]);
    const float x2 = bfu2f(r0[hh * 128 + d + 64]) + bfu2f(r1[hh * 128 + d + 64]);
    const float o1 = x1 * c - x2 * s, o2 = x2 * c + x1 * s;
    if (hh < 16) {
      Qb[(long)t * 2048 + hh * 128 + d] = __float2bfloat16(o1 * qscale);
      Qb[(long)t * 2048 + hh * 128 + d + 64] = __float2bfloat16(o2 * qscale);
    } else {
      Kb[t * 512 + (hh - 16) * 128 + d] = __float2bfloat16(o1);
      Kb[t * 512 + (hh - 16) * 128 + d + 64] = __float2bfloat16(o2);
    }
  }
}

// ---------------- Flash attention partials: swapped-QK in-register softmax ----------------
// S^T = mfma(K_frag, Q_frag): lane holds 16 P values of q-row (lane&15).
// K rows fed in sigma-order (key = kc*32 + (lr>>2)*8 + b*4 + (lr&3)) so the S output
// registers ARE the PV A-fragment (key == k-position). P never touches LDS.
// NOTE: launch_bounds(256,2) — NOT 4: the 64-VGPR cap from ",4" forced scratch
// spills (R6: FETCH+WRITE grew ~21MB, dur +10us). ~110 VGPR needs the 256 cap.
__global__ __launch_bounds__(256, 2) void attn_partial(const bf16* __restrict__ Qb,
                                                       const bf16* __restrict__ Kb,
                                                       const bf16* __restrict__ VbT,
                                                       bf16* __restrict__ Pctx,
                                                       float* __restrict__ ML) {
  const int h = blockIdx.x;
  const int qb = 31 - blockIdx.y;  // heavy blocks dispatch first
  const int z = blockIdx.z;
  const int kh = h >> 2;
  const int tid = threadIdx.x, lane = tid & 63, w = tid >> 6;
  const int pid = (h * 32 + qb) * 2 + z;

  const int nt = qb + 1;
  const int half = (nt + 1) >> 1;
  const int kt0 = z * half;
  const int kt1 = (z == 0) ? half : nt;

  if (kt0 >= kt1) {  // empty chunk: neutral ML + zeroed partial
    if (tid < 64) {
      ML[pid * 128 + tid] = -1e30f;
      ML[pid * 128 + 64 + tid] = 0.0f;
    }
    ushort4 z4 = make_ushort4(0, 0, 0, 0);
    ushort4* pz = (ushort4*)(Pctx + (long)pid * 8192);
    for (int j = tid; j < 2048; j += 256) pz[j] = z4;
    return;
  }

  __shared__ bf16 Kl[64 * 128];  // swizzle bits: (row&3)|((row&8)>>1)
  __shared__ bf16 Vt[128 * 64];  // swizzle bits: row&7

  const int lr = lane & 15, lh = lane >> 4;
  const int q0w = qb * 64 + w * 16;

  bh8 qf[4];
#pragma unroll
  for (int dc = 0; dc < 4; ++dc)
    qf[dc] = *(const bh8*)&Qb[(long)(q0w + lr) * 2048 + h * 128 + dc * 32 + lh * 8];

  f32x4 ctx[8];
#pragma unroll
  for (int i = 0; i < 8; ++i)
#pragma unroll
    for (int r = 0; r < 4; ++r) ctx[i][r] = 0.0f;
  float mrun = -1e30f, lrun = 0.0f;

  for (int kt = kt0; kt < kt1; ++kt) {
    __syncthreads();
    // stage K tile 64x128: linear LDS dest, source chunk-swizzled by (row&3)|((row&8)>>1)
    const long Kbase = ((long)(kt * 64) * 4 + kh) * 128;
#pragma unroll
    for (int i = 0; i < 4; ++i) {
      const int cb = i * 256 + w * 64;
      const int c = cb + lane;
      const int krow = c >> 4, s = c & 15;
      const int g = s ^ ((krow & 3) | ((krow & 8) >> 1));
      gload_lds16(Kb + Kbase + (long)krow * 512 + g * 8, (char*)Kl + cb * 16);
    }
    // stage V^T tile 128x64: source chunk-swizzled by row&7
    const long Vbase = (long)kh * 128 * 2048 + kt * 64;
#pragma unroll
    for (int i = 0; i < 4; ++i) {
      const int cb = i * 256 + w * 64;
      const int c = cb + lane;
      const int vrow = c >> 3, s = c & 7;
      gload_lds16(VbT + Vbase + (long)vrow * 2048 + (s ^ (vrow & 7)) * 8, (char*)Vt + cb * 16);
    }
    __syncthreads();

    // S^T = K . Q^T in sigma key-order; lane (lr,lh) reg (kc,b,r) holds
    // S[key = kc*32 + lh*8 + b*4 + r][q = lr]   (Q pre-scaled by 1/sqrt(D))
    f32x4 S[2][2];
#pragma unroll
    for (int kc = 0; kc < 2; ++kc)
#pragma unroll
      for (int b = 0; b < 2; ++b) {
#pragma unroll
        for (int r = 0; r < 4; ++r) S[kc][b][r] = 0.0f;
        const int key = kc * 32 + ((lr >> 2) << 3) + b * 4 + (lr & 3);
        const int kbase = key * 256 + lh * 16;
#pragma unroll
        for (int dc = 0; dc < 4; ++dc) {
          bh8 kf = *(const bh8*)((const char*)Kl + ((kbase + dc * 64) ^ ((lr & 7) << 4)));
          S[kc][b] = MFMA16(kf, qf[dc], S[kc][b]);
        }
      }

    // causal mask on the diagonal tile only
    if (kt == qb) {
      const int qg = q0w + lr;
#pragma unroll
      for (int kc = 0; kc < 2; ++kc)
#pragma unroll
        for (int b = 0; b < 2; ++b)
#pragma unroll
          for (int r = 0; r < 4; ++r) {
            const int kg = kt * 64 + kc * 32 + lh * 8 + b * 4 + r;
            if (kg > qg) S[kc][b][r] = -1e30f;
          }
    }

    // row max: 15 in-lane fmax + 2 shfl (row = q = lr)
    float pm = -1e30f;
#pragma unroll
    for (int kc = 0; kc < 2; ++kc)
#pragma unroll
      for (int b = 0; b < 2; ++b)
#pragma unroll
        for (int r = 0; r < 4; ++r) pm = fmaxf(pm, S[kc][b][r]);
    pm = fmaxf(pm, __shfl_xor(pm, 16, 64));
    pm = fmaxf(pm, __shfl_xor(pm, 32, 64));

    // defer-max: rescale only when some row grew past mrun + 4
    if (__any(pm > mrun + 4.0f)) {
      const float mnew = fmaxf(mrun, pm);
      const float alpha = __expf(mrun - mnew);
      mrun = mnew;
      lrun *= alpha;
      float a4[4];
#pragma unroll
      for (int r = 0; r < 4; ++r) a4[r] = __shfl(alpha, lh * 4 + r, 64);
#pragma unroll
      for (int i = 0; i < 8; ++i)
#pragma unroll
        for (int r = 0; r < 4; ++r) ctx[i][r] *= a4[r];
    }

    // P = exp(S - mrun), packed in-register as the PV A-fragment
    bh8 pa[2];
#pragma unroll
    for (int kc = 0; kc < 2; ++kc) {
      union { bh8 v; bf16 e[8]; } pk;
#pragma unroll
      for (int b = 0; b < 2; ++b)
#pragma unroll
        for (int r = 0; r < 4; ++r) {
          const float p = __expf(S[kc][b][r] - mrun);
          lrun += p;
          pk.e[b * 4 + r] = __float2bfloat16(p);
        }
      pa[kc] = pk.v;
    }

    // PV: ctx += P(16x64) * V(64x128)
#pragma unroll
    for (int kc = 0; kc < 2; ++kc)
#pragma unroll
      for (int dblk = 0; dblk < 8; ++dblk) {
        const int vrow = dblk * 16 + lr;
        const int voff = (vrow * 128 + kc * 64 + lh * 16) ^ ((lr & 7) << 4);
        bh8 vb = *(const bh8*)((const char*)Vt + voff);
        ctx[dblk] = MFMA16(pa[kc], vb, ctx[dblk]);
      }
  }

  // epilogue: reduce row sums (2 shfl), write unnormalized partial + (m,l)
  float l = lrun;
  l += __shfl_xor(l, 16, 64);
  l += __shfl_xor(l, 32, 64);
  if (lh == 0) {
    ML[pid * 128 + w * 16 + lr] = mrun;
    ML[pid * 128 + 64 + w * 16 + lr] = l;
  }
#pragma unroll
  for (int dblk = 0; dblk < 8; ++dblk)
#pragma unroll
    for (int r = 0; r < 4; ++r)
      Pctx[(long)pid * 8192 + (w * 16 + lh * 4 + r) * 128 + dblk * 16 + lr] =
          __float2bfloat16(ctx[dblk][r]);
}

// ---------------- merge 2 partials -> normalized ctx (bf16, [t][h*128+d]) ----------------
__global__ __launch_bounds__(256) void attn_merge(const bf16* __restrict__ Pctx,
                                                  const float* __restrict__ ML,
                                                  bf16* __restrict__ out) {
  const int h = blockIdx.x, qb = blockIdx.y;
  const int tid = threadIdx.x;
  const int r = tid >> 2, seg = tid & 3;
  const int pid0 = (h * 32 + qb) * 2;
  const float m0 = ML[pid0 * 128 + r], l0 = ML[pid0 * 128 + 64 + r];
  const float m1 = ML[pid0 * 128 + 128 + r], l1 = ML[pid0 * 128 + 192 + r];
  const float m = fmaxf(m0, m1);
  float a0 = __expf(m0 - m), a1 = __expf(m1 - m);
  const float inv = 1.0f / (l0 * a0 + l1 * a1);
  a0 *= inv;
  a1 *= inv;
  const ushort* p0 = (const ushort*)(Pctx + (long)pid0 * 8192 + r * 128 + seg * 32);
  const ushort* p1 = p0 + 8192;
  bf16* o = out + (long)(qb * 64 + r) * 2048 + h * 128 + seg * 32;
#pragma unroll
  for (int j = 0; j < 4; ++j) {
    union { bh8 v; ushort s[8]; } v0, v1;
    v0.v = *(const bh8*)(p0 + j * 8);
    v1.v = *(const bh8*)(p1 + j * 8);
    union { ushort4 u; bf16 b[4]; } o0, o1;
#pragma unroll
    for (int e = 0; e < 4; ++e) {
      o0.b[e] = __float2bfloat16(bfu2f(v0.s[e]) * a0 + bfu2f(v1.s[e]) * a1);
      o1.b[e] = __float2bfloat16(bfu2f(v0.s[e + 4]) * a0 + bfu2f(v1.s[e + 4]) * a1);
    }
    *(ushort4*)(o + j * 8) = o0.u;
    *(ushort4*)(o + j * 8 + 4) = o1.u;
  }
}

// ---------------- launch ----------------
extern "C" void kernel_launch(void* const* d_in, const int* in_sizes, int n_in,
                              void* d_out, int out_size, void* d_ws, size_t ws_size,
                              hipStream_t stream) {
  const float* hs = (const float*)d_in[0];
  const int* pos = (const int*)d_in[1];
  const float* Wqkv = (const float*)d_in[2];
  const float* Wo = (const float*)d_in[3];
  char* ws = (char*)d_ws;

  bf16* hsb = (bf16*)(ws);
  bf16* ctx = (bf16*)(ws);
  bf16* wqkvT = (bf16*)(ws + (8l << 20));
  bf16* Qb = (bf16*)(ws + (8l << 20));
  bf16* Kb = (bf16*)(ws + (16l << 20));
  bf16* VbT = (bf16*)(ws + (18l << 20));
  bf16* woT = (bf16*)(ws + (20l << 20));
  bf16* qkvP0 = (bf16*)(ws + (28l << 20));
  bf16* qkvP1 = (bf16*)(ws + (40l << 20));
  bf16* Pctx = (bf16*)(ws + (28l << 20));
  float* ML = (float*)(ws + (44l << 20));
  float* outP1 = (float*)(ws + (28l << 20));

  cast_f32_bf16<<<4096, 256, 0, stream>>>(hs, hsb, 2048 * 2048 / 4);
  transpose_cast<<<dim3(3072 / 32, 2048 / 32), 256, 0, stream>>>(Wqkv, wqkvT, 2048, 3072);
  transpose_cast<<<dim3(2048 / 32, 2048 / 32), 256, 0, stream>>>(Wo, woT, 2048, 2048);
  gemm_bt_sk<true><<<dim3(24, 16, 2), 256, 0, stream>>>(hsb, wqkvT, qkvP0, qkvP1,
                                                        2048, 3072, 2048, 16);
  rope_split<<<2048, 256, 0, stream>>>(qkvP0, qkvP1, pos, Qb, Kb, VbT);
  attn_partial<<<dim3(16, 32, 2), 256, 0, stream>>>(Qb, Kb, VbT, Pctx, ML);
  attn_merge<<<dim3(16, 32), 256, 0, stream>>>(Pctx, ML, ctx);
  gemm_bt_sk<false><<<dim3(16, 16, 2), 256, 0, stream>>>(ctx, woT, d_out, outP1,
                                                         2048, 2048, 2048, 16);
  out_reduce<<<4096, 256, 0, stream>>>((float*)d_out, outP1, 2048 * 2048 / 4);
}